// Round 8
// baseline (195.112 us; speedup 1.0000x reference)
//
#include <hip/hip_runtime.h>
#include <cstdint>
#include <cstddef>

#define N_TOKENS 65536
#define DIM 64
#define K_CODES 1024
#define NTH 256
#define TPB 64                  // tokens per block; 4 waves each own a code quarter
#define NBLK (N_TOKENS / TPB)   // 1024 blocks

// out layout (floats): [0]=loss, [1..4194304]=quantized, [4194305]=perplexity,
// [4194306..4259841]=indices
#define OFF_Q 1
#define OFF_PERP 4194305
#define OFF_IDX 4194306

// fp16-split error <~1.5e-6; reference fp32 rounding jitter <~1.6e-5; margin 2.5e-5
// (validated rounds 4-5: passed with absmax 3.8e-6)
#define MARGIN 2.5e-5f
// x scaled by 2^10, w by 2^16 (exact pow2) to keep fp16 splits normal
#define XSCALE 1024.0f
#define WSCALE 65536.0f
#define AINIT_SC -33554432.0f            // -0.5 * 2^26
#define D_UNSC  -2.9802322387695312e-08f // -2 * 2^-26 = -2^-25

// ws byte offsets
#define WS_LOSS   0        // double
#define WS_TICKET 8        // int
#define WS_COUNTS 16       // int[1024]
#define WS_WHI    4112     // _Float16[65536] row-major [code][k], scaled 2^16
#define WS_WLO    135184   // _Float16[65536]
#define WS_S2     266256   // float[1024] exact np-order ||w||^2

typedef _Float16 f16x8 __attribute__((ext_vector_type(8)));
typedef _Float16 f16x4 __attribute__((ext_vector_type(4)));
typedef float    f32x4 __attribute__((ext_vector_type(4)));

__device__ __forceinline__ float fmulr(float a, float b){ return __fmul_rn(a,b); }
__device__ __forceinline__ float faddr(float a, float b){ return __fadd_rn(a,b); }

__device__ __forceinline__ unsigned keyf(float f) {  // monotone float->u32
    unsigned u = __float_as_uint(f);
    return u ^ ((u & 0x80000000u) ? 0xffffffffu : 0x80000000u);
}

// split pre-scaled v into fp16 hi/lo (v - (float)h exact: residual <=13 sig bits)
__device__ __forceinline__ void split16(float v, _Float16& h, _Float16& l) {
    h = (_Float16)v;
    l = (_Float16)(v - (float)h);
}

// numpy (AVX512 pairwise) sum of 64 squares — validated bit-exact rounds 1-5
__device__ float sumsq64_np(const float* __restrict__ p) {
    float s[16];
    #pragma unroll
    for (int l = 0; l < 16; ++l) {
        float a0 = fmulr(p[l],      p[l]);
        float a1 = fmulr(p[l + 16], p[l + 16]);
        float a2 = fmulr(p[l + 32], p[l + 32]);
        float a3 = fmulr(p[l + 48], p[l + 48]);
        s[l] = faddr(faddr(a0, a1), faddr(a2, a3));
    }
    #pragma unroll
    for (int len = 8; len >= 1; len >>= 1)
        #pragma unroll
        for (int l = 0; l < len; ++l)
            s[l] = faddr(s[l], s[l + len]);
    return s[0];
}

// ---------------- prep: W -> row-major fp16 hi/lo (scaled), exact s2, zero accs --
__global__ void vq_prep(const float* __restrict__ W, _Float16* __restrict__ Whi,
                        _Float16* __restrict__ Wlo, float* __restrict__ s2g,
                        int* __restrict__ counts, int* __restrict__ ticket,
                        double* __restrict__ loss_acc) {
    int gid = blockIdx.x * NTH + threadIdx.x;   // 128 blocks -> 32768 threads
    if (gid < 16384) {                           // one float4 per thread
        f32x4 v = *(const f32x4*)(W + gid * 4);
        f16x4 h, l;
        #pragma unroll
        for (int j = 0; j < 4; ++j) {
            _Float16 hh, ll; split16(v[j] * WSCALE, hh, ll);
            h[j] = hh; l[j] = ll;
        }
        *(f16x4*)(Whi + gid * 4) = h;
        *(f16x4*)(Wlo + gid * 4) = l;
    }
    if (gid < K_CODES) { s2g[gid] = sumsq64_np(W + gid * 64); counts[gid] = 0; }
    if (gid == 0) { *loss_acc = 0.0; *ticket = 0; }
}

// ---------------- main: batched-chain MFMA scan + 4-way merge + fallback ---------
__global__ __launch_bounds__(NTH, 2)
void vq_main(const float* __restrict__ X, const float* __restrict__ W,
             const _Float16* __restrict__ WhiG, const _Float16* __restrict__ WloG,
             const float* __restrict__ s2g, float* __restrict__ out,
             double* __restrict__ loss_acc, int* __restrict__ counts,
             int* __restrict__ ticket) {
    __shared__ float m1v[4][TPB];
    __shared__ int   m1i[4][TPB];
    __shared__ float m2v[4][TPB];
    __shared__ int   fidx[TPB];
    __shared__ int   flist[TPB];
    __shared__ int   fcount, lastFlag;
    __shared__ double lred[4];

    const int tid  = threadIdx.x;
    const int lane = tid & 63, wave = tid >> 6;
    const int quad = lane >> 4, lrow = lane & 15;
    const int t0   = blockIdx.x * TPB;
    const int c0   = wave * 256;                 // this wave's code quarter

    if (tid == 0) fcount = 0;

    // ---- A fragments: global X -> registers (fp16 split, x 2^10); 64 tokens -----
    f16x8 a_h0[4], a_h1[4], a_l0[4], a_l1[4];
    #pragma unroll
    for (int rt = 0; rt < 4; ++rt) {
        const float* xrow = X + (size_t)(t0 + rt * 16 + lrow) * DIM;
        f32x4 v0 = *(const f32x4*)(xrow + quad * 8);
        f32x4 v1 = *(const f32x4*)(xrow + quad * 8 + 4);
        f32x4 v2 = *(const f32x4*)(xrow + 32 + quad * 8);
        f32x4 v3 = *(const f32x4*)(xrow + 32 + quad * 8 + 4);
        #pragma unroll
        for (int j = 0; j < 4; ++j) {
            _Float16 h, l;
            split16(v0[j] * XSCALE, h, l); a_h0[rt][j]     = h; a_l0[rt][j]     = l;
            split16(v1[j] * XSCALE, h, l); a_h0[rt][j + 4] = h; a_l0[rt][j + 4] = l;
            split16(v2[j] * XSCALE, h, l); a_h1[rt][j]     = h; a_l1[rt][j]     = l;
            split16(v3[j] * XSCALE, h, l); a_h1[rt][j + 4] = h; a_l1[rt][j + 4] = l;
        }
    }

    float r1v[16], r2v[16]; int r1i[16];
    #pragma unroll
    for (int ri = 0; ri < 16; ++ri) { r1v[ri] = 3.4e38f; r2v[ri] = 3.4e38f; r1i[ri] = 0x7fffffff; }

    // ---- 8 groups of 32 codes (2 ct-tiles), register dbuf, unroll-2 (cur static) -
    f16x8 bh0[2][2], bh1[2][2], bl0[2][2], bl1[2][2]; float s2v[2][2];
    #pragma unroll
    for (int ct = 0; ct < 2; ++ct) {             // load group 0
        int code = c0 + ct * 16 + lrow;
        const _Float16* ph = WhiG + code * 64 + quad * 8;
        const _Float16* pl = WloG + code * 64 + quad * 8;
        bh0[0][ct] = *(const f16x8*)ph; bh1[0][ct] = *(const f16x8*)(ph + 32);
        bl0[0][ct] = *(const f16x8*)pl; bl1[0][ct] = *(const f16x8*)(pl + 32);
        s2v[0][ct] = s2g[code];
    }
    #pragma unroll 2
    for (int g = 0; g < 8; ++g) {
        const int cur = g & 1;                   // static under unroll-2
        if (g < 7) {                             // prefetch group g+1
            #pragma unroll
            for (int ct = 0; ct < 2; ++ct) {
                int code = c0 + (g + 1) * 32 + ct * 16 + lrow;
                const _Float16* ph = WhiG + code * 64 + quad * 8;
                const _Float16* pl = WloG + code * 64 + quad * 8;
                bh0[cur ^ 1][ct] = *(const f16x8*)ph; bh1[cur ^ 1][ct] = *(const f16x8*)(ph + 32);
                bl0[cur ^ 1][ct] = *(const f16x8*)pl; bl1[cur ^ 1][ct] = *(const f16x8*)(pl + 32);
                s2v[cur ^ 1][ct] = s2g[code];
            }
        }
        // MFMA phase: 8 independent 6-chains (2 ct x 4 rt), 48 MFMA back-to-back
        f32x4 acc[2][4];
        #pragma unroll
        for (int ct = 0; ct < 2; ++ct) {
            float ainit = fmulr(s2v[cur][ct], AINIT_SC);   // -0.5*s2*2^26
            #pragma unroll
            for (int rt = 0; rt < 4; ++rt) {
                f32x4 a = {ainit, ainit, ainit, ainit};
                a = __builtin_amdgcn_mfma_f32_16x16x32_f16(a_h0[rt], bh0[cur][ct], a, 0, 0, 0);
                a = __builtin_amdgcn_mfma_f32_16x16x32_f16(a_h1[rt], bh1[cur][ct], a, 0, 0, 0);
                a = __builtin_amdgcn_mfma_f32_16x16x32_f16(a_h0[rt], bl0[cur][ct], a, 0, 0, 0);
                a = __builtin_amdgcn_mfma_f32_16x16x32_f16(a_h1[rt], bl1[cur][ct], a, 0, 0, 0);
                a = __builtin_amdgcn_mfma_f32_16x16x32_f16(a_l0[rt], bh0[cur][ct], a, 0, 0, 0);
                a = __builtin_amdgcn_mfma_f32_16x16x32_f16(a_l1[rt], bh1[cur][ct], a, 0, 0, 0);
                acc[ct][rt] = a;
            }
        }
        // argmin phase: 32 top-2 updates (codes ascending: ct0 then ct1)
        #pragma unroll
        for (int ct = 0; ct < 2; ++ct) {
            int jc = c0 + g * 32 + ct * 16 + lrow;
            #pragma unroll
            for (int rt = 0; rt < 4; ++rt) {
                #pragma unroll
                for (int r = 0; r < 4; ++r) {
                    float d = fmulr(acc[ct][rt][r], D_UNSC);   // s2 - 2x.w
                    int ri = rt * 4 + r;
                    bool lt = d < r1v[ri];                     // strict: earliest code on ties
                    r2v[ri] = fminf(r2v[ri], fmaxf(d, r1v[ri]));  // med3 second-best
                    r1v[ri] = lt ? d : r1v[ri];
                    r1i[ri] = lt ? jc : r1i[ri];
                }
            }
        }
    }

    // ---- butterfly top-2 merge across the 16 lrow lanes (codes disjoint) --------
    #pragma unroll
    for (int m = 1; m <= 8; m <<= 1) {
        #pragma unroll
        for (int ri = 0; ri < 16; ++ri) {
            float o1v = __shfl_xor(r1v[ri], m, 64);
            int   o1i = __shfl_xor(r1i[ri], m, 64);
            float o2v = __shfl_xor(r2v[ri], m, 64);
            bool take = (o1v < r1v[ri]) || (o1v == r1v[ri] && o1i < r1i[ri]);
            float loser = take ? r1v[ri] : o1v;
            r2v[ri] = fminf(fminf(r2v[ri], o2v), loser);
            if (take) { r1v[ri] = o1v; r1i[ri] = o1i; }
        }
    }
    if (lrow == 0) {
        #pragma unroll
        for (int ri = 0; ri < 16; ++ri) {
            int rt = ri >> 2, r = ri & 3;
            int tloc = rt * 16 + quad * 4 + r;
            m1v[wave][tloc] = r1v[ri];
            m1i[wave][tloc] = r1i[ri];
            m2v[wave][tloc] = r2v[ri];
        }
    }
    __syncthreads();

    // ---- merge 4 code-quarters per token (ascending q: earliest code on ties) ---
    if (tid < TPB) {
        float b1v = m1v[0][tid]; int b1i = m1i[0][tid]; float b2v = m2v[0][tid];
        #pragma unroll
        for (int q = 1; q < 4; ++q) {
            float v = m1v[q][tid];
            bool take = v < b1v;                 // strict: lower quarter wins ties
            float loser = take ? b1v : v;
            b2v = fminf(fminf(b2v, m2v[q][tid]), loser);
            b1v = take ? v : b1v;
            b1i = take ? m1i[q][tid] : b1i;
        }
        bool fb = (b2v - b1v) < MARGIN;
        fidx[tid] = fb ? (b1i | (int)0x80000000) : b1i;
        if (fb) { int p = atomicAdd(&fcount, 1); flist[p] = tid; }
    }
    __syncthreads();

    // ---- epilogue for certain tokens, float4-vectorized ------------------------
    double lsum = 0.0;
    #pragma unroll
    for (int i = 0; i < 4; ++i) {
        int e4 = tid + NTH * i;                  // 0..1023 float4 groups
        int t = e4 >> 4, d4 = (e4 & 15) * 4;
        int iv = fidx[t];
        if (iv >= 0) {
            f32x4 q = *(const f32x4*)&W[iv * 64 + d4];
            f32x4 x = *(const f32x4*)&X[(size_t)(t0 + t) * 64 + d4];
            *(f32x4*)&out[(size_t)OFF_Q + (size_t)(t0 + t) * 64 + d4] = q;
            #pragma unroll
            for (int c = 0; c < 4; ++c) {
                float df = __fsub_rn(q[c], x[c]);
                lsum += (double)fmulr(df, df);
            }
        }
    }
    #pragma unroll
    for (int off = 32; off >= 1; off >>= 1) lsum += __shfl_down(lsum, off, 64);
    if (lane == 0) lred[wave] = lsum;
    if (tid < TPB) {
        int iv = fidx[tid];
        if (iv >= 0) {
            atomicAdd(&counts[iv], 1);
            out[(size_t)OFF_IDX + t0 + tid] = (float)iv;
        }
    }
    __syncthreads();
    if (tid == 0) atomicAdd(loss_acc, lred[0] + lred[1] + lred[2] + lred[3]);

    // ---- in-block exact fallback: one wave per marginal token, W from L2 --------
    // bit-exact round-1 arithmetic: sequential-k fp32 FMA chain, np tie-break
    for (int fi = wave; fi < fcount; fi += 4) {
        int t = flist[fi];
        int gtok = t0 + t;
        float s1v = sumsq64_np(X + (size_t)gtok * 64);   // broadcast loads
        f32x4 xr[16];
        #pragma unroll
        for (int kb = 0; kb < 16; ++kb)
            xr[kb] = *(const f32x4*)(X + (size_t)gtok * 64 + kb * 4);
        unsigned long long best = ~0ULL;
        #pragma unroll 1
        for (int c16 = 0; c16 < 16; ++c16) {
            int code = lane * 16 + c16;
            const float* wr = W + code * 64;
            float acc = 0.0f;
            #pragma unroll
            for (int kb = 0; kb < 16; ++kb) {
                f32x4 wv = *(const f32x4*)(wr + kb * 4);
                acc = __builtin_fmaf(xr[kb][0], wv[0], acc);
                acc = __builtin_fmaf(xr[kb][1], wv[1], acc);
                acc = __builtin_fmaf(xr[kb][2], wv[2], acc);
                acc = __builtin_fmaf(xr[kb][3], wv[3], acc);
            }
            float d = faddr(faddr(s1v, s2g[code]), fmulr(-2.0f, acc));
            unsigned long long pk = ((unsigned long long)keyf(d) << 32) | (unsigned)code;
            best = pk < best ? pk : best;
        }
        #pragma unroll
        for (int m = 32; m >= 1; m >>= 1) {
            unsigned long long o = __shfl_xor(best, m, 64);
            best = o < best ? o : best;
        }
        int idx = (int)(best & 0xffffffffu);
        float q = W[idx * 64 + lane];
        float x = X[(size_t)gtok * 64 + lane];
        out[(size_t)OFF_Q + (size_t)gtok * 64 + lane] = q;
        float df = __fsub_rn(q, x);
        double ls = (double)fmulr(df, df);
        #pragma unroll
        for (int m = 32; m >= 1; m >>= 1) ls += __shfl_xor(ls, m, 64);
        if (lane == 0) {
            out[(size_t)OFF_IDX + gtok] = (float)idx;
            atomicAdd(&counts[idx], 1);
            atomicAdd(loss_acc, ls);
        }
    }

    // ---- merged finale: last block to finish computes loss & perplexity ---------
    __syncthreads();
    if (tid == 0) {
        __threadfence();
        int old = atomicAdd(ticket, 1);
        lastFlag = (old == NBLK - 1) ? 1 : 0;
    }
    __syncthreads();
    if (lastFlag) {
        double h = 0.0;
        for (int j = tid; j < K_CODES; j += NTH) {
            int c = atomicAdd(&counts[j], 0);        // device-coherent read
            double p = (double)c / 65536.0;
            h += p * log(p + 1e-10);
        }
        #pragma unroll
        for (int off = 32; off >= 1; off >>= 1) h += __shfl_down(h, off, 64);
        if (lane == 0) lred[wave] = h;
        __syncthreads();
        if (tid == 0) {
            double H = lred[0] + lred[1] + lred[2] + lred[3];
            out[OFF_PERP] = (float)exp(-H);
            double ls = atomicAdd(loss_acc, 0.0);    // device-coherent read
            float Lf = (float)(ls / 4194304.0);
            out[0] = faddr(Lf, fmulr(0.25f, Lf));
        }
    }
}

extern "C" void kernel_launch(void* const* d_in, const int* in_sizes, int n_in,
                              void* d_out, int out_size, void* d_ws, size_t ws_size,
                              hipStream_t stream) {
    const float* X = (const float*)d_in[0];
    const float* W = (const float*)d_in[1];
    float* out = (float*)d_out;
    char* ws = (char*)d_ws;
    double* loss_acc = (double*)(ws + WS_LOSS);
    int* ticket = (int*)(ws + WS_TICKET);
    int* counts = (int*)(ws + WS_COUNTS);
    _Float16* Whi = (_Float16*)(ws + WS_WHI);
    _Float16* Wlo = (_Float16*)(ws + WS_WLO);
    float* s2g = (float*)(ws + WS_S2);

    vq_prep<<<128, NTH, 0, stream>>>(W, Whi, Wlo, s2g, counts, ticket, loss_acc);
    vq_main<<<NBLK, NTH, 0, stream>>>(X, W, Whi, Wlo, s2g, out,
                                      loss_acc, counts, ticket);
}